// Round 7
// baseline (63.575 us; speedup 1.0000x reference)
//
#include <hip/hip_runtime.h>
#include <math.h>

#define D_MODEL 2048
#define NUM_EXP 64
#define TOKB    32                 // tokens per block
#define BK      64                 // k-floats per pipeline step
#define STEPS   (D_MODEL / BK)     // 32

typedef _Float16 f16x4 __attribute__((ext_vector_type(4)));
typedef _Float16 f16x8 __attribute__((ext_vector_type(8)));
typedef float    f32x4 __attribute__((ext_vector_type(4)));

// ---------------------------------------------------------------------------
// k0: convert W[64][2048] fp32 -> fragment-linear f16 hi/lo buffers.
// Split: W = wh + wl * 2^-12, wl stored scaled by 4096 (fp16-normal range).
// Fragment layout (A-operand of mfma_f32_16x16x32_f16):
//   frag (kc, mf): lane l holds A[m = mf*16 + (l&15)][k = kc*32 + (l>>4)*8 + j]
//   stored flat at whf[(kc*4 + mf)*64 + l]. This is the "pre-swizzled global"
//   pattern: k1's LDS copy is LINEAR and its frag ds_read is conflict-free.
// ---------------------------------------------------------------------------
__global__ __launch_bounds__(256)
void k0_convw(const float* __restrict__ W, f16x8* __restrict__ whf,
              f16x8* __restrict__ wlf) {
    const int t    = blockIdx.x * 256 + threadIdx.x;   // 0..16383
    const int lane = t & 63;
    const int mf   = (t >> 6) & 3;
    const int kc   = t >> 8;                           // 0..63
    const int m    = mf * 16 + (lane & 15);
    const int k0   = kc * 32 + ((lane >> 4) << 3);
    const float* src = W + (size_t)m * D_MODEL + k0;
    f16x8 h, l;
#pragma unroll
    for (int j = 0; j < 8; ++j) {
        float v = src[j];
        _Float16 hh = (_Float16)v;
        h[j] = hh;
        l[j] = (_Float16)((v - (float)hh) * 4096.f);   // exact residual, scaled
    }
    whf[t] = h;
    wlf[t] = l;
}

// ---------------------------------------------------------------------------
// k1: canonical LDS-staged fused router.
// Block = 512 thr (8 waves) = 32 tokens x 64 experts x full K.
// Wave wid owns output frag (tf = wid&1 token-16-group, mf = wid>>1
// expert-16-group); full-K accumulation in ONE acc pair (8 VGPR).
// Per K-step (BK=64): stage x coalesced (1 float4/thread) -> fp16 hi/lo split
// ONCE -> XOR-swizzled LDS; stage W-frags linearly (contiguous 1KB wave
// loads, conflict-free frag reads). 2-phase double buffer, one barrier/step.
// Epilogue: logits tile in LDS -> per-wave softmax + top-2 (lax.top_k tie
// rule: lower index wins) + per-block expert partials. Deterministic.
// Grid: N/32 = 512 blocks; LDS 60KB -> 2 blocks/CU -> 4 waves/SIMD.
// ---------------------------------------------------------------------------
__global__ __launch_bounds__(512, 4)
void k1_fused(const float* __restrict__ x, const f16x8* __restrict__ whf,
              const f16x8* __restrict__ wlf, float* __restrict__ out,
              float* __restrict__ p_part, float* __restrict__ f_part, int N) {
    const int tid  = threadIdx.x;
    const int lane = tid & 63;
    const int wid  = tid >> 6;          // 0..7
    const int tok0 = blockIdx.x * TOKB;
    const int tf   = wid & 1;           // token 16-group
    const int mf   = wid >> 1;          // expert 16-group

    __shared__ _Float16 xh_s[2][TOKB][BK];      // 8 KB
    __shared__ _Float16 xl_s[2][TOKB][BK];      // 8 KB
    __shared__ f16x8    w_s[2][2][512];         // 32 KB  [buf][hi/lo][c*256+mf*64+lane]
    __shared__ float    ep[TOKB][NUM_EXP];      // 8 KB
    __shared__ float    p_red[8][64], f_red[8][64];

    // x staging map: thread -> (row, float4-col); fully coalesced.
    const int srow = tid >> 4;          // 0..31
    const int sc4  = tid & 15;          // 16 float4 per 64-float row
    const float* xsrc = x + (size_t)(tok0 + srow) * D_MODEL + sc4 * 4;
    const int    ko   = (sc4 * 8) ^ ((srow & 7) << 4);   // swizzled byte off

    f32x4 acc1 = f32x4{0.f, 0.f, 0.f, 0.f};
    f32x4 acc2 = f32x4{0.f, 0.f, 0.f, 0.f};

    auto stage = [&](int buf, int s) {
        // --- x: 1 float4/thread, split to fp16 hi/lo, swizzled ds_write ---
        const float4 v = *(const float4*)(xsrc + (size_t)s * BK);
        const float vf[4] = {v.x, v.y, v.z, v.w};
        f16x4 h, l;
#pragma unroll
        for (int j = 0; j < 4; ++j) {
            _Float16 hh = (_Float16)vf[j];
            h[j] = hh;
            l[j] = (_Float16)((vf[j] - (float)hh) * 4096.f);
        }
        *(f16x4*)((char*)&xh_s[buf][srow][0] + ko) = h;
        *(f16x4*)((char*)&xl_s[buf][srow][0] + ko) = l;
        // --- W: linear copy of fragment-linear global (1 f16x8/thread each) ---
        w_s[buf][0][tid] = whf[(size_t)(2 * s) * 256 + tid];
        w_s[buf][1][tid] = wlf[(size_t)(2 * s) * 256 + tid];
    };

    const int ft = lane & 15;           // token within frag
    const int fs = lane >> 4;           // k-segment
    auto compute = [&](int buf) {
        const char* xhb = (const char*)&xh_s[buf][tf * 16 + ft][0];
        const char* xlb = (const char*)&xl_s[buf][tf * 16 + ft][0];
#pragma unroll
        for (int c = 0; c < 2; ++c) {
            const int o = (c * 64 + fs * 16) ^ ((ft & 7) << 4);
            const f16x8 xh = *(const f16x8*)(xhb + o);
            const f16x8 xl = *(const f16x8*)(xlb + o);
            const f16x8 wh = w_s[buf][0][c * 256 + mf * 64 + lane];
            const f16x8 wl = w_s[buf][1][c * 256 + mf * 64 + lane];
            acc1 = __builtin_amdgcn_mfma_f32_16x16x32_f16(wh, xh, acc1, 0, 0, 0);
            acc2 = __builtin_amdgcn_mfma_f32_16x16x32_f16(wh, xl, acc2, 0, 0, 0);
            acc2 = __builtin_amdgcn_mfma_f32_16x16x32_f16(wl, xh, acc2, 0, 0, 0);
        }
    };

    stage(0, 0);
    __syncthreads();
    for (int s = 0; s < STEPS; ++s) {
        if (s + 1 < STEPS) stage((s + 1) & 1, s + 1);
        compute(s & 1);
        __syncthreads();
    }

    // --- epilogue: full logits -> LDS tile --------------------------------
    // C layout: col = lane&15 = token, row = (lane>>4)*4 + r = expert.
    {
        f32x4 o = acc1 + acc2 * (1.f / 4096.f);
        *(f32x4*)&ep[tf * 16 + ft][mf * 16 + fs * 4] = o;
    }
    __syncthreads();

    // --- softmax + top-2, 4 tokens per wave (lane == expert) --------------
    float pacc = 0.f, facc = 0.f;
#pragma unroll
    for (int i = 0; i < 4; ++i) {
        const int tl = wid * 4 + i;
        float logit = ep[tl][lane];

        float m = logit;
        for (int off = 32; off; off >>= 1) m = fmaxf(m, __shfl_xor(m, off));
        float p = __expf(logit - m);
        float S = p;
        for (int off = 32; off; off >>= 1) S += __shfl_xor(S, off);
        float prob = p / S;

        float bv = logit; int bi = lane;
        for (int off = 32; off; off >>= 1) {
            float ov = __shfl_xor(bv, off);
            int   oi = __shfl_xor(bi, off);
            if (ov > bv || (ov == bv && oi < bi)) { bv = ov; bi = oi; }
        }
        float cv = (lane == bi) ? -INFINITY : logit;
        int   ci = lane;
        for (int off = 32; off; off >>= 1) {
            float ov = __shfl_xor(cv, off);
            int   oi = __shfl_xor(ci, off);
            if (ov > cv || (ov == cv && oi < ci)) { cv = ov; ci = oi; }
        }

        if (lane == 0) {
            const int gt = tok0 + tl;
            float w0 = 1.f / (1.f + __expf(cv - bv));
            out[(size_t)gt * 2]     = w0;
            out[(size_t)gt * 2 + 1] = 1.f - w0;
            out[(size_t)2 * N + gt * 2]     = (float)bi;
            out[(size_t)2 * N + gt * 2 + 1] = (float)ci;
        }

        pacc += prob;
        facc += (lane == bi ? 1.f : 0.f) + (lane == ci ? 1.f : 0.f);
    }

    p_red[wid][lane] = pacc;
    f_red[wid][lane] = facc;
    __syncthreads();
    if (wid == 0) {
        float sp = 0.f, sf = 0.f;
#pragma unroll
        for (int w = 0; w < 8; ++w) { sp += p_red[w][lane]; sf += f_red[w][lane]; }
        p_part[(size_t)blockIdx.x * NUM_EXP + lane] = sp;
        f_part[(size_t)blockIdx.x * NUM_EXP + lane] = sf;
    }
}

// ---------------------------------------------------------------------------
// k3: deterministic aux-loss reduction over per-block partials.
// aux = E * sum_i (f_sum_i / N) * (p_sum_i / N)
// ---------------------------------------------------------------------------
__global__ __launch_bounds__(1024)
void k3_aux(const float* __restrict__ p_part, const float* __restrict__ f_part,
            float* __restrict__ out, int N, int B2) {
    const int lane = threadIdx.x & 63;
    const int wid  = threadIdx.x >> 6;    // 0..15
    float sp = 0.f, sf = 0.f;
    for (int b = wid; b < B2; b += 16) {
        sp += p_part[(size_t)b * NUM_EXP + lane];
        sf += f_part[(size_t)b * NUM_EXP + lane];
    }
    __shared__ float lsp[16][64];
    __shared__ float lsf[16][64];
    lsp[wid][lane] = sp;
    lsf[wid][lane] = sf;
    __syncthreads();
    if (wid == 0) {
        float tsp = 0.f, tsf = 0.f;
#pragma unroll
        for (int w = 0; w < 16; ++w) { tsp += lsp[w][lane]; tsf += lsf[w][lane]; }
        float v = tsp * tsf;
        for (int off = 32; off; off >>= 1) v += __shfl_xor(v, off);
        if (lane == 0)
            out[(size_t)4 * N] = (float)NUM_EXP * v / ((float)N * (float)N);
    }
}

extern "C" void kernel_launch(void* const* d_in, const int* in_sizes, int n_in,
                              void* d_out, int out_size, void* d_ws, size_t ws_size,
                              hipStream_t stream) {
    const float* x = (const float*)d_in[0];
    const float* W = (const float*)d_in[1];
    float* out = (float*)d_out;

    const int N  = in_sizes[0] / D_MODEL;   // 16384
    const int B1 = N / TOKB;                // 512 fused blocks

    // ws layout: [whf 256KB][wlf 256KB][p_part 128KB][f_part 128KB]
    f16x8* whf = (f16x8*)d_ws;
    f16x8* wlf = whf + 16384;
    float* p_part = (float*)(wlf + 16384);
    float* f_part = p_part + (size_t)B1 * NUM_EXP;

    k0_convw<<<64, 256, 0, stream>>>(W, whf, wlf);
    k1_fused<<<B1, 512, 0, stream>>>(x, whf, wlf, out, p_part, f_part, N);
    k3_aux<<<1, 1024, 0, stream>>>(p_part, f_part, out, N, B1);
}